// Round 3
// baseline (63.044 us; speedup 1.0000x reference)
//
#include <hip/hip_runtime.h>

// Problem dims (fixed by reference setup_inputs):
#define BATCH 1024
#define NSEQ  512
#define NF    64
#define TBL_N (NSEQ + 1)   // counts range 0..512
#define HIST_BINS 1024     // ids in [0,1000)

typedef float f32x4 __attribute__((ext_vector_type(4)));  // clang vector: OK for nontemporal builtin

// ---------------------------------------------------------------------------
// Kernel 1: lookup table  tbl[c][g] = b2[g] + sum_f relu(c*W1[f]+b1[f]) * W2[f][g]
// ---------------------------------------------------------------------------
__global__ void build_table_kernel(const float* __restrict__ W1,
                                   const float* __restrict__ b1,
                                   const float* __restrict__ W2,
                                   const float* __restrict__ b2,
                                   float* __restrict__ tbl) {
    const int c = blockIdx.x;     // count value 0..512
    const int g = threadIdx.x;    // output feature 0..63
    const float cf = (float)c;
    float acc = b2[g];
#pragma unroll 8
    for (int f = 0; f < NF; ++f) {
        float h = fmaxf(cf * W1[f] + b1[f], 0.0f);
        acc += h * W2[f * NF + g];
    }
    tbl[c * NF + g] = acc;
}

// ---------------------------------------------------------------------------
// Kernel 2a: per batch row histogram -> packed per-position counts (ushort4).
// One block per batch row, 256 threads. Output: 1024*512*8 B = 4 MB.
// ---------------------------------------------------------------------------
__global__ __launch_bounds__(256) void count_kernel(
        const int* __restrict__ src_ids,
        const int* __restrict__ dst_ids,
        ushort4* __restrict__ counts) {
    __shared__ int s_src[NSEQ];
    __shared__ int s_dst[NSEQ];
    __shared__ int hist_s[HIST_BINS];
    __shared__ int hist_d[HIST_BINS];

    const int b = blockIdx.x;
    const int t = threadIdx.x;

#pragma unroll
    for (int i = t; i < HIST_BINS; i += 256) { hist_s[i] = 0; hist_d[i] = 0; }
#pragma unroll
    for (int i = t; i < NSEQ; i += 256) {
        s_src[i] = src_ids[(size_t)b * NSEQ + i];
        s_dst[i] = dst_ids[(size_t)b * NSEQ + i];
    }
    __syncthreads();

#pragma unroll
    for (int i = t; i < NSEQ; i += 256) {
        int si = s_src[i], di = s_dst[i];
        if (si >= 0) atomicAdd(&hist_s[si], 1);
        if (di >= 0) atomicAdd(&hist_d[di], 1);
    }
    __syncthreads();

#pragma unroll
    for (int i = t; i < NSEQ; i += 256) {
        int si = s_src[i], di = s_dst[i];
        ushort4 p;
        p.x = (si >= 0) ? (unsigned short)hist_s[si] : 0;  // src_in_src
        p.y = (si >= 0) ? (unsigned short)hist_d[si] : 0;  // src_in_dst
        p.z = (di >= 0) ? (unsigned short)hist_d[di] : 0;  // dst_in_dst
        p.w = (di >= 0) ? (unsigned short)hist_s[di] : 0;  // dst_in_src
        counts[(size_t)b * NSEQ + i] = p;
    }
}

// ---------------------------------------------------------------------------
// Kernel 2b: pure streaming expand. Grid-stride over float4 elements.
// No LDS, no barriers; table gathers hit L1 (counts are tiny); nt stores.
// ---------------------------------------------------------------------------
__global__ __launch_bounds__(256) void expand_kernel(
        const ushort4* __restrict__ counts,
        const float* __restrict__ tbl,
        float* __restrict__ out_src,
        float* __restrict__ out_dst) {
    const f32x4* __restrict__ tbl4 = (const f32x4*)tbl;
    f32x4* __restrict__ o0 = (f32x4*)out_src;
    f32x4* __restrict__ o1 = (f32x4*)out_dst;
    const long total  = (long)BATCH * NSEQ * (NF / 4);      // 8,388,608
    const long stride = (long)gridDim.x * blockDim.x;
    for (long e = (long)blockIdx.x * blockDim.x + threadIdx.x; e < total; e += stride) {
        const long n  = e >> 4;          // position index (16 float4 per position)
        const int  f4 = (int)(e & 15);
        const ushort4 c = counts[n];
        f32x4 a0 = tbl4[(int)c.x * (NF / 4) + f4];
        f32x4 a1 = tbl4[(int)c.y * (NF / 4) + f4];
        __builtin_nontemporal_store(a0 + a1, &o0[e]);
        f32x4 d0 = tbl4[(int)c.z * (NF / 4) + f4];
        f32x4 d1 = tbl4[(int)c.w * (NF / 4) + f4];
        __builtin_nontemporal_store(d0 + d1, &o1[e]);
    }
}

// ---------------------------------------------------------------------------
// Fallback (R1 fused kernel) if ws_size is too small for the counts buffer.
// ---------------------------------------------------------------------------
__global__ __launch_bounds__(256) void cooc_encode_kernel(
        const int* __restrict__ src_ids,
        const int* __restrict__ dst_ids,
        const float* __restrict__ tbl,
        float* __restrict__ out_src,
        float* __restrict__ out_dst) {
    __shared__ int s_src[NSEQ];
    __shared__ int s_dst[NSEQ];
    __shared__ int hist_s[HIST_BINS];
    __shared__ int hist_d[HIST_BINS];
    __shared__ int c_ss[NSEQ], c_sd[NSEQ], c_dd[NSEQ], c_ds[NSEQ];

    const int b = blockIdx.x;
    const int t = threadIdx.x;

#pragma unroll
    for (int i = t; i < HIST_BINS; i += 256) { hist_s[i] = 0; hist_d[i] = 0; }
#pragma unroll
    for (int i = t; i < NSEQ; i += 256) {
        s_src[i] = src_ids[(size_t)b * NSEQ + i];
        s_dst[i] = dst_ids[(size_t)b * NSEQ + i];
    }
    __syncthreads();
#pragma unroll
    for (int i = t; i < NSEQ; i += 256) {
        int si = s_src[i], di = s_dst[i];
        if (si >= 0) atomicAdd(&hist_s[si], 1);
        if (di >= 0) atomicAdd(&hist_d[di], 1);
    }
    __syncthreads();
#pragma unroll
    for (int i = t; i < NSEQ; i += 256) {
        int si = s_src[i], di = s_dst[i];
        c_ss[i] = (si >= 0) ? hist_s[si] : 0;
        c_sd[i] = (si >= 0) ? hist_d[si] : 0;
        c_dd[i] = (di >= 0) ? hist_d[di] : 0;
        c_ds[i] = (di >= 0) ? hist_s[di] : 0;
    }
    __syncthreads();

    const float4* __restrict__ tbl4 = (const float4*)tbl;
    float4* __restrict__ o0 = (float4*)(out_src + (size_t)b * NSEQ * NF);
    float4* __restrict__ o1 = (float4*)(out_dst + (size_t)b * NSEQ * NF);
    const int NV = NSEQ * NF / 4;
#pragma unroll 4
    for (int e = t; e < NV; e += 256) {
        int n  = e >> 4;
        int f4 = e & 15;
        float4 a0 = tbl4[c_ss[n] * (NF / 4) + f4];
        float4 a1 = tbl4[c_sd[n] * (NF / 4) + f4];
        o0[e] = make_float4(a0.x + a1.x, a0.y + a1.y, a0.z + a1.z, a0.w + a1.w);
        float4 d0 = tbl4[c_dd[n] * (NF / 4) + f4];
        float4 d1 = tbl4[c_ds[n] * (NF / 4) + f4];
        o1[e] = make_float4(d0.x + d1.x, d0.y + d1.y, d0.z + d1.z, d0.w + d1.w);
    }
}

extern "C" void kernel_launch(void* const* d_in, const int* in_sizes, int n_in,
                              void* d_out, int out_size, void* d_ws, size_t ws_size,
                              hipStream_t stream) {
    const int*   src_ids = (const int*)d_in[0];
    const int*   dst_ids = (const int*)d_in[1];
    const float* W1 = (const float*)d_in[2];   // [1, F]
    const float* b1 = (const float*)d_in[3];   // [F]
    const float* W2 = (const float*)d_in[4];   // [F, F]
    const float* b2 = (const float*)d_in[5];   // [F]

    float* out_src = (float*)d_out;                               // [B, N, F]
    float* out_dst = (float*)d_out + (size_t)BATCH * NSEQ * NF;   // [B, N, F]

    // Workspace layout: [table: TBL_N*NF f32][pad][counts: B*N ushort4]
    const size_t tbl_bytes    = (size_t)TBL_N * NF * sizeof(float);      // 131,328
    const size_t counts_off   = (tbl_bytes + 255) & ~(size_t)255;        // 131,584
    const size_t counts_bytes = (size_t)BATCH * NSEQ * sizeof(ushort4);  // 4 MB

    float* tbl = (float*)d_ws;

    build_table_kernel<<<TBL_N, NF, 0, stream>>>(W1, b1, W2, b2, tbl);

    if (ws_size >= counts_off + counts_bytes) {
        ushort4* counts = (ushort4*)((char*)d_ws + counts_off);
        count_kernel<<<BATCH, 256, 0, stream>>>(src_ids, dst_ids, counts);
        expand_kernel<<<2048, 256, 0, stream>>>(counts, tbl, out_src, out_dst);
    } else {
        cooc_encode_kernel<<<BATCH, 256, 0, stream>>>(src_ids, dst_ids, tbl,
                                                      out_src, out_dst);
    }
}

// Round 4
// 51.410 us; speedup vs baseline: 1.2263x; 1.2263x over previous
//
#include <hip/hip_runtime.h>

// Problem dims (fixed by reference setup_inputs):
#define BATCH 1024
#define NSEQ  512
#define NF    64
#define TBL_N (NSEQ + 1)   // counts range 0..512
#define HIST_BINS 1024     // ids in [0,1000)

// Table part of prep kernel: 4 c-values per block, 64 threads each.
#define TBL_BLOCKS ((TBL_N + 3) / 4)   // 129

// ---------------------------------------------------------------------------
// Kernel 1 (prep): blocks [0,BATCH): per-row histogram -> packed counts.
//                  blocks [BATCH, BATCH+TBL_BLOCKS): build lookup table
//                  tbl[c][g] = b2[g] + sum_f relu(c*W1[f]+b1[f]) * W2[f][g]
// ---------------------------------------------------------------------------
__global__ __launch_bounds__(256) void prep_kernel(
        const int* __restrict__ src_ids,
        const int* __restrict__ dst_ids,
        const float* __restrict__ W1,
        const float* __restrict__ b1,
        const float* __restrict__ W2,
        const float* __restrict__ b2,
        float* __restrict__ tbl,
        ushort4* __restrict__ counts) {
    const int t = threadIdx.x;

    if (blockIdx.x >= BATCH) {
        // ---- table builder ----
        const int c = (blockIdx.x - BATCH) * 4 + (t >> 6);  // count value
        const int g = t & 63;                               // feature
        if (c < TBL_N) {
            const float cf = (float)c;
            float acc = b2[g];
#pragma unroll 8
            for (int f = 0; f < NF; ++f) {
                float h = fmaxf(cf * W1[f] + b1[f], 0.0f);
                acc += h * W2[f * NF + g];
            }
            tbl[c * NF + g] = acc;
        }
        return;
    }

    // ---- per-row histogram counts ----
    __shared__ int s_src[NSEQ];
    __shared__ int s_dst[NSEQ];
    __shared__ int hist_s[HIST_BINS];
    __shared__ int hist_d[HIST_BINS];

    const int b = blockIdx.x;

#pragma unroll
    for (int i = t; i < HIST_BINS; i += 256) { hist_s[i] = 0; hist_d[i] = 0; }
#pragma unroll
    for (int i = t; i < NSEQ; i += 256) {
        s_src[i] = src_ids[(size_t)b * NSEQ + i];
        s_dst[i] = dst_ids[(size_t)b * NSEQ + i];
    }
    __syncthreads();

#pragma unroll
    for (int i = t; i < NSEQ; i += 256) {
        int si = s_src[i], di = s_dst[i];
        if (si >= 0) atomicAdd(&hist_s[si], 1);
        if (di >= 0) atomicAdd(&hist_d[di], 1);
    }
    __syncthreads();

#pragma unroll
    for (int i = t; i < NSEQ; i += 256) {
        int si = s_src[i], di = s_dst[i];
        ushort4 p;
        p.x = (si >= 0) ? (unsigned short)hist_s[si] : 0;  // src_in_src
        p.y = (si >= 0) ? (unsigned short)hist_d[si] : 0;  // src_in_dst
        p.z = (di >= 0) ? (unsigned short)hist_d[di] : 0;  // dst_in_dst
        p.w = (di >= 0) ? (unsigned short)hist_s[di] : 0;  // dst_in_src
        counts[(size_t)b * NSEQ + i] = p;
    }
}

// ---------------------------------------------------------------------------
// Kernel 2 (expand): 2048 blocks; block b owns one batch-row of ONE output
// tensor (b<1024 -> out_src row b, else out_dst row b-1024): 128 KB
// contiguous stores. Counts row staged in 4 KB LDS; table rows from L1.
// Plain float4 stores (nt stores regressed -11 us in R3).
// ---------------------------------------------------------------------------
__global__ __launch_bounds__(256) void expand_kernel(
        const ushort4* __restrict__ counts,
        const float* __restrict__ tbl,
        float* __restrict__ out_src,
        float* __restrict__ out_dst) {
    __shared__ ushort2 s_cnt[NSEQ];   // the (c1,c2) pair for this tensor

    const int t = threadIdx.x;
    const int which = blockIdx.x >> 10;          // 0 = src, 1 = dst
    const int row   = blockIdx.x & 1023;         // batch row

    const ushort4* __restrict__ crow = counts + (size_t)row * NSEQ;
#pragma unroll
    for (int i = t; i < NSEQ; i += 256) {
        ushort4 c = crow[i];
        s_cnt[i] = (which == 0) ? make_ushort2(c.x, c.y) : make_ushort2(c.z, c.w);
    }
    __syncthreads();

    const float4* __restrict__ tbl4 = (const float4*)tbl;
    float* base = (which == 0) ? out_src : out_dst;
    float4* __restrict__ o = (float4*)(base + (size_t)row * NSEQ * NF);

    const int NV = NSEQ * NF / 4;   // 8192 float4 per block
#pragma unroll 8
    for (int e = t; e < NV; e += 256) {
        int n  = e >> 4;            // position (16 float4 per position)
        int f4 = e & 15;
        ushort2 c = s_cnt[n];
        float4 a0 = tbl4[(int)c.x * (NF / 4) + f4];
        float4 a1 = tbl4[(int)c.y * (NF / 4) + f4];
        o[e] = make_float4(a0.x + a1.x, a0.y + a1.y, a0.z + a1.z, a0.w + a1.w);
    }
}

// ---------------------------------------------------------------------------
// Fallback (R1 fused kernel, 52 us) if ws_size is too small.
// ---------------------------------------------------------------------------
__global__ void build_table_kernel(const float* __restrict__ W1,
                                   const float* __restrict__ b1,
                                   const float* __restrict__ W2,
                                   const float* __restrict__ b2,
                                   float* __restrict__ tbl) {
    const int c = blockIdx.x;
    const int g = threadIdx.x;
    const float cf = (float)c;
    float acc = b2[g];
#pragma unroll 8
    for (int f = 0; f < NF; ++f) {
        float h = fmaxf(cf * W1[f] + b1[f], 0.0f);
        acc += h * W2[f * NF + g];
    }
    tbl[c * NF + g] = acc;
}

__global__ __launch_bounds__(256) void cooc_encode_kernel(
        const int* __restrict__ src_ids,
        const int* __restrict__ dst_ids,
        const float* __restrict__ tbl,
        float* __restrict__ out_src,
        float* __restrict__ out_dst) {
    __shared__ int s_src[NSEQ];
    __shared__ int s_dst[NSEQ];
    __shared__ int hist_s[HIST_BINS];
    __shared__ int hist_d[HIST_BINS];
    __shared__ int c_ss[NSEQ], c_sd[NSEQ], c_dd[NSEQ], c_ds[NSEQ];

    const int b = blockIdx.x;
    const int t = threadIdx.x;

#pragma unroll
    for (int i = t; i < HIST_BINS; i += 256) { hist_s[i] = 0; hist_d[i] = 0; }
#pragma unroll
    for (int i = t; i < NSEQ; i += 256) {
        s_src[i] = src_ids[(size_t)b * NSEQ + i];
        s_dst[i] = dst_ids[(size_t)b * NSEQ + i];
    }
    __syncthreads();
#pragma unroll
    for (int i = t; i < NSEQ; i += 256) {
        int si = s_src[i], di = s_dst[i];
        if (si >= 0) atomicAdd(&hist_s[si], 1);
        if (di >= 0) atomicAdd(&hist_d[di], 1);
    }
    __syncthreads();
#pragma unroll
    for (int i = t; i < NSEQ; i += 256) {
        int si = s_src[i], di = s_dst[i];
        c_ss[i] = (si >= 0) ? hist_s[si] : 0;
        c_sd[i] = (si >= 0) ? hist_d[si] : 0;
        c_dd[i] = (di >= 0) ? hist_d[di] : 0;
        c_ds[i] = (di >= 0) ? hist_s[di] : 0;
    }
    __syncthreads();

    const float4* __restrict__ tbl4 = (const float4*)tbl;
    float4* __restrict__ o0 = (float4*)(out_src + (size_t)b * NSEQ * NF);
    float4* __restrict__ o1 = (float4*)(out_dst + (size_t)b * NSEQ * NF);
    const int NV = NSEQ * NF / 4;
#pragma unroll 4
    for (int e = t; e < NV; e += 256) {
        int n  = e >> 4;
        int f4 = e & 15;
        float4 a0 = tbl4[c_ss[n] * (NF / 4) + f4];
        float4 a1 = tbl4[c_sd[n] * (NF / 4) + f4];
        o0[e] = make_float4(a0.x + a1.x, a0.y + a1.y, a0.z + a1.z, a0.w + a1.w);
        float4 d0 = tbl4[c_dd[n] * (NF / 4) + f4];
        float4 d1 = tbl4[c_ds[n] * (NF / 4) + f4];
        o1[e] = make_float4(d0.x + d1.x, d0.y + d1.y, d0.z + d1.z, d0.w + d1.w);
    }
}

extern "C" void kernel_launch(void* const* d_in, const int* in_sizes, int n_in,
                              void* d_out, int out_size, void* d_ws, size_t ws_size,
                              hipStream_t stream) {
    const int*   src_ids = (const int*)d_in[0];
    const int*   dst_ids = (const int*)d_in[1];
    const float* W1 = (const float*)d_in[2];   // [1, F]
    const float* b1 = (const float*)d_in[3];   // [F]
    const float* W2 = (const float*)d_in[4];   // [F, F]
    const float* b2 = (const float*)d_in[5];   // [F]

    float* out_src = (float*)d_out;                               // [B, N, F]
    float* out_dst = (float*)d_out + (size_t)BATCH * NSEQ * NF;   // [B, N, F]

    // Workspace layout: [table: TBL_N*NF f32][pad][counts: B*N ushort4]
    const size_t tbl_bytes    = (size_t)TBL_N * NF * sizeof(float);      // 131,328
    const size_t counts_off   = (tbl_bytes + 255) & ~(size_t)255;        // 131,584
    const size_t counts_bytes = (size_t)BATCH * NSEQ * sizeof(ushort4);  // 4 MB

    float* tbl = (float*)d_ws;

    if (ws_size >= counts_off + counts_bytes) {
        ushort4* counts = (ushort4*)((char*)d_ws + counts_off);
        prep_kernel<<<BATCH + TBL_BLOCKS, 256, 0, stream>>>(
            src_ids, dst_ids, W1, b1, W2, b2, tbl, counts);
        expand_kernel<<<2 * BATCH, 256, 0, stream>>>(counts, tbl, out_src, out_dst);
    } else {
        build_table_kernel<<<TBL_N, NF, 0, stream>>>(W1, b1, W2, b2, tbl);
        cooc_encode_kernel<<<BATCH, 256, 0, stream>>>(src_ids, dst_ids, tbl,
                                                      out_src, out_dst);
    }
}

// Round 5
// 51.320 us; speedup vs baseline: 1.2285x; 1.0018x over previous
//
#include <hip/hip_runtime.h>

// Problem dims (fixed by reference setup_inputs):
#define BATCH 1024
#define NSEQ  512
#define NF    64
#define TBL_N (NSEQ + 1)   // counts range 0..512
#define HIST_BINS 1024     // ids in [0,1000)

#define TBL_BLOCKS ((TBL_N + 3) / 4)   // 129 blocks x (4 c-values * 64 threads)

// ---------------------------------------------------------------------------
// Kernel 1: lookup table  tbl[c][g] = b2[g] + sum_f relu(c*W1[f]+b1[f]) * W2[f][g]
// Tiny: ~1-2 us. Only dependency of the expand kernel.
// ---------------------------------------------------------------------------
__global__ __launch_bounds__(256) void build_table_kernel(
        const float* __restrict__ W1,
        const float* __restrict__ b1,
        const float* __restrict__ W2,
        const float* __restrict__ b2,
        float* __restrict__ tbl) {
    const int c = blockIdx.x * 4 + (threadIdx.x >> 6);  // count value
    const int g = threadIdx.x & 63;                     // feature
    if (c >= TBL_N) return;
    const float cf = (float)c;
    float acc = b2[g];
#pragma unroll 8
    for (int f = 0; f < NF; ++f) {
        float h = fmaxf(cf * W1[f] + b1[f], 0.0f);
        acc += h * W2[f * NF + g];
    }
    tbl[c * NF + g] = acc;
}

// ---------------------------------------------------------------------------
// Kernel 2: self-contained writer. Block 2b+w owns batch-row b of tensor w
// (w=0 -> out_src, w=1 -> out_dst). Each block builds BOTH row histograms
// itself (removes the serialized prep kernel + counts round-trip), then
// streams 128 KB of contiguous float4 stores gathering table rows from L1.
// 2048 blocks = 8/CU = full occupancy; LDS 14 KB.
// ---------------------------------------------------------------------------
__global__ __launch_bounds__(256) void expand_kernel(
        const int* __restrict__ src_ids,
        const int* __restrict__ dst_ids,
        const float* __restrict__ tbl,
        float* __restrict__ out) {
    __shared__ int     s_src[NSEQ];
    __shared__ int     s_dst[NSEQ];
    __shared__ int     hist_s[HIST_BINS];
    __shared__ int     hist_d[HIST_BINS];
    __shared__ ushort2 s_cnt[NSEQ];

    const int t     = threadIdx.x;
    const int which = blockIdx.x & 1;    // 0 = src-tensor, 1 = dst-tensor
    const int row   = blockIdx.x >> 1;   // batch row

    // zero histograms
#pragma unroll
    for (int i = t; i < HIST_BINS; i += 256) { hist_s[i] = 0; hist_d[i] = 0; }
    // stage both id rows
#pragma unroll
    for (int i = t; i < NSEQ; i += 256) {
        s_src[i] = src_ids[(size_t)row * NSEQ + i];
        s_dst[i] = dst_ids[(size_t)row * NSEQ + i];
    }
    __syncthreads();

    // build both histograms (guard padded id = -1)
#pragma unroll
    for (int i = t; i < NSEQ; i += 256) {
        int si = s_src[i], di = s_dst[i];
        if (si >= 0) atomicAdd(&hist_s[si], 1);
        if (di >= 0) atomicAdd(&hist_d[di], 1);
    }
    __syncthreads();

    // per-position (c1,c2) for THIS tensor
#pragma unroll
    for (int i = t; i < NSEQ; i += 256) {
        int id = (which == 0) ? s_src[i] : s_dst[i];
        ushort2 c;
        if (id >= 0) {
            c.x = (unsigned short)((which == 0) ? hist_s[id] : hist_d[id]); // own
            c.y = (unsigned short)((which == 0) ? hist_d[id] : hist_s[id]); // cross
        } else {
            c.x = 0; c.y = 0;
        }
        s_cnt[i] = c;
    }
    __syncthreads();

    // stream: out[row,n,:] = tbl[c1] + tbl[c2]
    const float4* __restrict__ tbl4 = (const float4*)tbl;
    float4* __restrict__ o = (float4*)(out + ((size_t)which * BATCH + row) * NSEQ * NF);
    const int NV = NSEQ * NF / 4;   // 8192 float4 per block
#pragma unroll 8
    for (int e = t; e < NV; e += 256) {
        int n  = e >> 4;            // position (16 float4 per position)
        int f4 = e & 15;
        ushort2 c = s_cnt[n];
        float4 a0 = tbl4[((int)c.x << 4) + f4];
        float4 a1 = tbl4[((int)c.y << 4) + f4];
        o[e] = make_float4(a0.x + a1.x, a0.y + a1.y, a0.z + a1.z, a0.w + a1.w);
    }
}

extern "C" void kernel_launch(void* const* d_in, const int* in_sizes, int n_in,
                              void* d_out, int out_size, void* d_ws, size_t ws_size,
                              hipStream_t stream) {
    const int*   src_ids = (const int*)d_in[0];
    const int*   dst_ids = (const int*)d_in[1];
    const float* W1 = (const float*)d_in[2];   // [1, F]
    const float* b1 = (const float*)d_in[3];   // [F]
    const float* W2 = (const float*)d_in[4];   // [F, F]
    const float* b2 = (const float*)d_in[5];   // [F]

    float* out = (float*)d_out;     // [2, B, N, F] flat (src tensor then dst tensor)
    float* tbl = (float*)d_ws;      // TBL_N * NF floats = 131,328 B

    build_table_kernel<<<TBL_BLOCKS, 256, 0, stream>>>(W1, b1, W2, b2, tbl);
    expand_kernel<<<2 * BATCH, 256, 0, stream>>>(src_ids, dst_ids, tbl, out);
}